// Round 1
// baseline (16.244 us; speedup 1.0000x reference)
//
#include <hip/hip_runtime.h>
#include <cmath>

#define BATCH 4
#define SEQLEN 2048
#define DMODEL 64
#define NTOK (BATCH * SEQLEN)          // 8192 tokens
#define TOK_PER_WAVE 4
#define WAVES_PER_BLOCK 4
#define NBLOCKS (NTOK / (TOK_PER_WAVE * WAVES_PER_BLOCK))  // 512

// y[tok, d] = x[tok, d] * softplus(x@W1+b1)[tok, d] * sum_n (x@W2+b2)[tok,n]*(x@W3+b3)[tok,n]
__global__ __launch_bounds__(256, 2) void s6_fused_kernel(
    const float* __restrict__ x,
    const float* __restrict__ W1, const float* __restrict__ b1,
    const float* __restrict__ W2, const float* __restrict__ b2,
    const float* __restrict__ W3, const float* __restrict__ b3,
    float* __restrict__ y)
{
    __shared__ float sW[3][DMODEL * DMODEL];   // 3 * 16 KiB = 48 KiB
    __shared__ float sB[3][DMODEL];

    const int tid = threadIdx.x;

    // Stage weights to LDS: 3 * 4096 floats = 3 * 1024 float4; 256 threads -> 4 each.
    {
        const float4* g0 = (const float4*)W1;
        const float4* g1 = (const float4*)W2;
        const float4* g2 = (const float4*)W3;
        float4* l0 = (float4*)sW[0];
        float4* l1 = (float4*)sW[1];
        float4* l2 = (float4*)sW[2];
        #pragma unroll
        for (int i = 0; i < 4; ++i) {
            const int idx = tid + 256 * i;
            l0[idx] = g0[idx];
            l1[idx] = g1[idx];
            l2[idx] = g2[idx];
        }
        if (tid < DMODEL) {
            sB[0][tid] = b1[tid];
            sB[1][tid] = b2[tid];
            sB[2][tid] = b3[tid];
        }
    }
    __syncthreads();

    const int lane = tid & 63;
    const int wave = tid >> 6;
    const int tok0 = (blockIdx.x * WAVES_PER_BLOCK + wave) * TOK_PER_WAVE;

    float xv[TOK_PER_WAVE], a1[TOK_PER_WAVE], a2[TOK_PER_WAVE], a3[TOK_PER_WAVE];
    #pragma unroll
    for (int t = 0; t < TOK_PER_WAVE; ++t) {
        xv[t] = x[(tok0 + t) * DMODEL + lane];
        a1[t] = sB[0][lane];
        a2[t] = sB[1][lane];
        a3[t] = sB[2][lane];
    }

    // k-loop: 3 LDS reads amortized over 12 FMAs (4 tokens x 3 matvecs).
    #pragma unroll
    for (int k = 0; k < DMODEL; ++k) {
        const float w1 = sW[0][k * DMODEL + lane];
        const float w2 = sW[1][k * DMODEL + lane];
        const float w3 = sW[2][k * DMODEL + lane];
        #pragma unroll
        for (int t = 0; t < TOK_PER_WAVE; ++t) {
            const float xk = __shfl(xv[t], k);   // uniform k -> readlane broadcast
            a1[t] = fmaf(xk, w1, a1[t]);
            a2[t] = fmaf(xk, w2, a2[t]);
            a3[t] = fmaf(xk, w3, a3[t]);
        }
    }

    #pragma unroll
    for (int t = 0; t < TOK_PER_WAVE; ++t) {
        const float delta = log1pf(expf(a1[t]));     // softplus
        float prod = a2[t] * a3[t];
        // wave64 all-reduce sum
        #pragma unroll
        for (int off = 32; off > 0; off >>= 1)
            prod += __shfl_xor(prod, off);
        y[(tok0 + t) * DMODEL + lane] = xv[t] * delta * prod;
    }
}

extern "C" void kernel_launch(void* const* d_in, const int* in_sizes, int n_in,
                              void* d_out, int out_size, void* d_ws, size_t ws_size,
                              hipStream_t stream) {
    const float* x  = (const float*)d_in[0];
    const float* W1 = (const float*)d_in[1];
    const float* b1 = (const float*)d_in[2];
    const float* W2 = (const float*)d_in[3];
    const float* b2 = (const float*)d_in[4];
    const float* W3 = (const float*)d_in[5];
    const float* b3 = (const float*)d_in[6];
    // d_in[7] = A: provably unused (dA * 0.0 == 0 for finite dA)
    float* y = (float*)d_out;

    s6_fused_kernel<<<NBLOCKS, 256, 0, stream>>>(x, W1, b1, W2, b2, W3, b3, y);
}

// Round 2
// 14.841 us; speedup vs baseline: 1.0945x; 1.0945x over previous
//
#include <hip/hip_runtime.h>
#include <cmath>

#define BATCH 4
#define SEQLEN 2048
#define DMODEL 64
#define NTOK (BATCH * SEQLEN)      // 8192 tokens
#define TOK_PER_WAVE 8
#define WAVES_PER_BLOCK 4
#define TOK_PER_BLOCK (TOK_PER_WAVE * WAVES_PER_BLOCK)   // 32
#define NBLOCKS (NTOK / TOK_PER_BLOCK)                   // 256 = 1/CU
#define WROW 68   // padded LDS row stride (dwords): 272 B = 17*16 B -> aligned b128, 2-way-free banks

// y[tok, d] = x[tok, d] * softplus(x@W1+b1)[tok, d] * sum_n (x@W2+b2)[tok,n]*(x@W3+b3)[tok,n]
__global__ __launch_bounds__(256, 1) void s6_fused_kernel(
    const float* __restrict__ x,
    const float* __restrict__ W1, const float* __restrict__ b1,
    const float* __restrict__ W2, const float* __restrict__ b2,
    const float* __restrict__ W3, const float* __restrict__ b3,
    float* __restrict__ y)
{
    // Transposed weights: sWT[m][d*WROW + k] = Wm[k*64 + d]
    __shared__ float sWT[3][DMODEL * WROW];   // 3 * 17.4 KB = 52.2 KB

    const int tid = threadIdx.x;

    {
        const float4* gm[3] = { (const float4*)W1, (const float4*)W2, (const float4*)W3 };
        #pragma unroll
        for (int m = 0; m < 3; ++m) {
            #pragma unroll
            for (int i0 = 0; i0 < 4; ++i0) {
                const int i = tid + 256 * i0;          // 1024 float4 per matrix
                const float4 w = gm[m][i];
                const int k  = i >> 4;                 // source row (contraction dim)
                const int d0 = (i & 15) << 2;          // source col group
                sWT[m][(d0 + 0) * WROW + k] = w.x;
                sWT[m][(d0 + 1) * WROW + k] = w.y;
                sWT[m][(d0 + 2) * WROW + k] = w.z;
                sWT[m][(d0 + 3) * WROW + k] = w.w;
            }
        }
    }

    const int lane = tid & 63;
    const int wave = tid >> 6;
    // Wave-uniform token base (readfirstlane -> enables scalar loads of x rows)
    const int tok0 = __builtin_amdgcn_readfirstlane(
        (blockIdx.x * WAVES_PER_BLOCK + wave) * TOK_PER_WAVE);
    const float* __restrict__ xb = x + (size_t)tok0 * DMODEL;

    // Per-lane x values (for the final elementwise scale) - coalesced vector loads
    float xv[TOK_PER_WAVE];
    #pragma unroll
    for (int t = 0; t < TOK_PER_WAVE; ++t)
        xv[t] = x[(size_t)(tok0 + t) * DMODEL + lane];

    float a1[TOK_PER_WAVE], a2[TOK_PER_WAVE], a3[TOK_PER_WAVE];
    const float bb1 = b1[lane], bb2 = b2[lane], bb3 = b3[lane];
    #pragma unroll
    for (int t = 0; t < TOK_PER_WAVE; ++t) { a1[t] = bb1; a2[t] = bb2; a3[t] = bb3; }

    __syncthreads();

    const float* __restrict__ r1 = &sWT[0][lane * WROW];
    const float* __restrict__ r2 = &sWT[1][lane * WROW];
    const float* __restrict__ r3 = &sWT[2][lane * WROW];

    #pragma unroll
    for (int k0 = 0; k0 < DMODEL; k0 += 4) {
        const float4 w1 = *(const float4*)(r1 + k0);
        const float4 w2 = *(const float4*)(r2 + k0);
        const float4 w3 = *(const float4*)(r3 + k0);
        #pragma unroll
        for (int t = 0; t < TOK_PER_WAVE; ++t) {
            const float* xr = xb + t * DMODEL + k0;    // wave-uniform -> s_load
            const float x0 = xr[0], x1 = xr[1], x2 = xr[2], x3 = xr[3];
            a1[t] = fmaf(x3, w1.w, fmaf(x2, w1.z, fmaf(x1, w1.y, fmaf(x0, w1.x, a1[t]))));
            a2[t] = fmaf(x3, w2.w, fmaf(x2, w2.z, fmaf(x1, w2.y, fmaf(x0, w2.x, a2[t]))));
            a3[t] = fmaf(x3, w3.w, fmaf(x2, w3.z, fmaf(x1, w3.y, fmaf(x0, w3.x, a3[t]))));
        }
    }

    #pragma unroll
    for (int t = 0; t < TOK_PER_WAVE; ++t) {
        const float delta = log1pf(expf(a1[t]));       // softplus
        float prod = a2[t] * a3[t];
        #pragma unroll
        for (int off = 32; off > 0; off >>= 1)
            prod += __shfl_xor(prod, off);             // sum over n (64 lanes)
        y[(size_t)(tok0 + t) * DMODEL + lane] = xv[t] * delta * prod;
    }
}

extern "C" void kernel_launch(void* const* d_in, const int* in_sizes, int n_in,
                              void* d_out, int out_size, void* d_ws, size_t ws_size,
                              hipStream_t stream) {
    const float* x  = (const float*)d_in[0];
    const float* W1 = (const float*)d_in[1];
    const float* b1 = (const float*)d_in[2];
    const float* W2 = (const float*)d_in[3];
    const float* b2 = (const float*)d_in[4];
    const float* W3 = (const float*)d_in[5];
    const float* b3 = (const float*)d_in[6];
    // d_in[7] = A: provably unused (dA * 0.0 == 0 for finite dA)
    float* y = (float*)d_out;

    s6_fused_kernel<<<NBLOCKS, 256, 0, stream>>>(x, W1, b1, W2, b2, W3, b3, y);
}

// Round 3
// 13.368 us; speedup vs baseline: 1.2151x; 1.1102x over previous
//
#include <hip/hip_runtime.h>
#include <cmath>

#define BATCH 4
#define SEQLEN 2048
#define DMODEL 64
#define NTOK (BATCH * SEQLEN)          // 8192 tokens
#define TOK_PER_WAVE 4
#define WAVES_PER_BLOCK 4
#define TOK_PER_BLOCK (TOK_PER_WAVE * WAVES_PER_BLOCK)   // 16
#define NBLOCKS (NTOK / TOK_PER_BLOCK)                   // 512 -> 2 blocks/CU

// y[tok, d] = x[tok, d] * softplus(x@W1+b1)[tok, d] * sum_n (x@W2+b2)[tok,n]*(x@W3+b3)[tok,n]
//
// LDS layout (per matrix, 64x64 f32, XOR-swizzled, no padding):
//   element (d, k) at dword  d*64 + (((k>>2) ^ ((d>>2)&7)) << 2) + (k&3)
// -> staging scatter-writes 2-way bank aliased (free), compute ds_read_b128 2-way (free).
__global__ __launch_bounds__(256, 2) void s6_fused_kernel(
    const float* __restrict__ x,
    const float* __restrict__ W1, const float* __restrict__ b1,
    const float* __restrict__ W2, const float* __restrict__ b2,
    const float* __restrict__ W3, const float* __restrict__ b3,
    float* __restrict__ y)
{
    __shared__ float sW[3][DMODEL * DMODEL];   // 48 KiB

    const int tid = threadIdx.x;
    const int lane = tid & 63;
    const int wave = tid >> 6;

    // ---- Stage 1: issue all global weight loads (independent, b128, coalesced)
    float4 wreg[3][4];
    {
        const float4* g0 = (const float4*)W1;
        const float4* g1 = (const float4*)W2;
        const float4* g2 = (const float4*)W3;
        #pragma unroll
        for (int i0 = 0; i0 < 4; ++i0) {
            const int i = tid + 256 * i0;
            wreg[0][i0] = g0[i];
            wreg[1][i0] = g1[i];
            wreg[2][i0] = g2[i];
        }
    }

    // Wave-uniform token base (readfirstlane -> scalar loads of x rows)
    const int tok0 = __builtin_amdgcn_readfirstlane(
        (blockIdx.x * WAVES_PER_BLOCK + wave) * TOK_PER_WAVE);
    const float* __restrict__ xb = x + (size_t)tok0 * DMODEL;

    // Per-lane x values for the final elementwise scale (coalesced)
    float xv[TOK_PER_WAVE];
    #pragma unroll
    for (int t = 0; t < TOK_PER_WAVE; ++t)
        xv[t] = x[(size_t)(tok0 + t) * DMODEL + lane];

    const float bb1 = b1[lane], bb2 = b2[lane], bb3 = b3[lane];

    // ---- Stage 2: swizzled scatter into LDS
    #pragma unroll
    for (int m = 0; m < 3; ++m) {
        #pragma unroll
        for (int i0 = 0; i0 < 4; ++i0) {
            const int i  = tid + 256 * i0;
            const int k  = i >> 4;                 // source row (contraction dim)
            const int d0 = (i & 15) << 2;          // source col group
            const int slot = (((k >> 2) ^ (i & 7)) << 2) + (k & 3);
            const float* w = (const float*)&wreg[m][i0];
            float* base = sW[m];
            #pragma unroll
            for (int j = 0; j < 4; ++j)
                base[(d0 + j) * DMODEL + slot] = w[j];
        }
    }

    float a1[TOK_PER_WAVE], a2[TOK_PER_WAVE], a3[TOK_PER_WAVE];
    #pragma unroll
    for (int t = 0; t < TOK_PER_WAVE; ++t) { a1[t] = bb1; a2[t] = bb2; a3[t] = bb3; }

    __syncthreads();

    // ---- k-loop: per wave 48 ds_read_b128 (2-way, free) + scalar x loads + f32 FMA
    const int swz = (lane >> 2) & 7;
    const float* __restrict__ r1 = sW[0] + lane * DMODEL;
    const float* __restrict__ r2 = sW[1] + lane * DMODEL;
    const float* __restrict__ r3 = sW[2] + lane * DMODEL;

    #pragma unroll
    for (int kk = 0; kk < DMODEL / 4; ++kk) {
        const int off = (kk ^ swz) << 2;           // swizzled 16B slot; elements k=4kk..4kk+3
        const float4 w1 = *(const float4*)(r1 + off);
        const float4 w2 = *(const float4*)(r2 + off);
        const float4 w3 = *(const float4*)(r3 + off);
        #pragma unroll
        for (int t = 0; t < TOK_PER_WAVE; ++t) {
            const float* xr = xb + t * DMODEL + kk * 4;   // wave-uniform -> s_load_dwordx4
            const float x0 = xr[0], x1 = xr[1], x2 = xr[2], x3 = xr[3];
            a1[t] = fmaf(x3, w1.w, fmaf(x2, w1.z, fmaf(x1, w1.y, fmaf(x0, w1.x, a1[t]))));
            a2[t] = fmaf(x3, w2.w, fmaf(x2, w2.z, fmaf(x1, w2.y, fmaf(x0, w2.x, a2[t]))));
            a3[t] = fmaf(x3, w3.w, fmaf(x2, w3.z, fmaf(x1, w3.y, fmaf(x0, w3.x, a3[t]))));
        }
    }

    #pragma unroll
    for (int t = 0; t < TOK_PER_WAVE; ++t) {
        const float delta = log1pf(expf(a1[t]));   // softplus
        float prod = a2[t] * a3[t];
        #pragma unroll
        for (int off = 32; off > 0; off >>= 1)
            prod += __shfl_xor(prod, off);         // sum over n (64 lanes)
        y[(size_t)(tok0 + t) * DMODEL + lane] = xv[t] * delta * prod;
    }
}

extern "C" void kernel_launch(void* const* d_in, const int* in_sizes, int n_in,
                              void* d_out, int out_size, void* d_ws, size_t ws_size,
                              hipStream_t stream) {
    const float* x  = (const float*)d_in[0];
    const float* W1 = (const float*)d_in[1];
    const float* b1 = (const float*)d_in[2];
    const float* W2 = (const float*)d_in[3];
    const float* b2 = (const float*)d_in[4];
    const float* W3 = (const float*)d_in[5];
    const float* b3 = (const float*)d_in[6];
    // d_in[7] = A: provably unused (dA * 0.0 == 0 for finite dA)
    float* y = (float*)d_out;

    s6_fused_kernel<<<NBLOCKS, 256, 0, stream>>>(x, W1, b1, W2, b2, W3, b3, y);
}